// Round 3
// baseline (89503.937 us; speedup 1.0000x reference)
//
#include <hip/hip_runtime.h>

#define NWG 256
#define WGS 512

typedef __attribute__((ext_vector_type(4))) float facc4;
typedef __attribute__((ext_vector_type(8))) short bfrag8;

#define MFMA_BF16 __builtin_amdgcn_mfma_f32_16x16x32_bf16

constexpr int B_ = 128, T_ = 512, I_ = 128, H_ = 1024;
constexpr int G_ = 4 * H_;  // 4096

// ---------------- workspace layout (bytes) ----------------
constexpr size_t OFF_BAR  = 0;        // 8192 reserved (padded barrier lines)
constexpr size_t OFF_H1F  = 8192;
constexpr size_t OFF_H2F  = OFF_H1F + 2ull * B_ * H_ * 4;
constexpr size_t OFF_C1   = OFF_H2F + 2ull * B_ * H_ * 4;
constexpr size_t OFF_C2   = OFF_C1 + (size_t)B_ * H_ * 4;
constexpr size_t OFF_X1F  = OFF_C2 + (size_t)B_ * H_ * 4;
constexpr size_t OFF_X2F  = OFF_X1F + (size_t)B_ * I_ * 4;
constexpr size_t OFF_H1S  = OFF_X2F + (size_t)B_ * H_ * 4;
constexpr size_t OFF_H2S  = OFF_H1S + 2ull * B_ * H_ * 2;
constexpr size_t OFF_X1S  = OFF_H2S + 2ull * B_ * H_ * 2;
constexpr size_t OFF_X2S  = OFF_X1S + (size_t)B_ * I_ * 2;
constexpr size_t OFF_BS1  = OFF_X2S + (size_t)B_ * H_ * 2;
constexpr size_t OFF_BS2  = OFF_BS1 + (size_t)G_ * 4;
constexpr size_t ZERO_BYTES = OFF_BS2 + (size_t)G_ * 4;
// bf16 weights (converted in-kernel each launch), L2-resident afterwards
constexpr size_t OFF_WQ1  = ZERO_BYTES;                         // 3*I*H
constexpr size_t OFF_WR1  = OFF_WQ1 + 3ull * I_ * H_ * 2;       // 2*H*I
constexpr size_t OFF_WIH1 = OFF_WR1 + 2ull * H_ * I_ * 2;       // G*I
constexpr size_t OFF_WHH1 = OFF_WIH1 + (size_t)G_ * I_ * 2;     // G*H
constexpr size_t OFF_WQ2  = OFF_WHH1 + (size_t)G_ * H_ * 2;     // 3*H*H
constexpr size_t OFF_WR2  = OFF_WQ2 + 3ull * H_ * H_ * 2;       // 2*H*H
constexpr size_t OFF_WIH2 = OFF_WR2 + 2ull * H_ * H_ * 2;       // G*H
constexpr size_t OFF_WHH2 = OFF_WIH2 + (size_t)G_ * H_ * 2;     // G*H

// ---------------- dynamic LDS ----------------
// All row strides are == 16 B (mod 128 B) -> 16-row b128 reads are 2-way (free).
constexpr int LSTR_MOG = 1032;  // mog A (16 rows) / W (32 rows), K=1024
constexpr int LSTR_C1  = 1160;  // cell1 A, K=1152
constexpr int LSTR_C2  = 2056;  // cell2 A, K=2048
constexpr int LSTR_W   = 264;   // cell W chunk, 128 rows x <=256 k
constexpr int LSTR_R1  = 136;   // mog1-R A (128 rows) / W (16 rows), K=128
constexpr size_t A_OFF   = 0;                    // 16*2056*2   = 65792
constexpr size_t W_OFF   = 65792;                // 128*264*2   = 67584
constexpr size_t RED_OFF = W_OFF + 67584;        // 8*4*64*4    = 8192
constexpr size_t DYN_LDS = RED_OFF + 8192;       // 141568 < 160 KiB

struct GBar {
  unsigned leaf[32][32];  // one counter per 128B line
  unsigned root[32];
  unsigned gen[32];
};

__device__ __forceinline__ float sigf(float x) { return 1.0f / (1.0f + __expf(-x)); }

__device__ __forceinline__ unsigned short f2bf(float f) {
  union { float f; unsigned u; } v; v.f = f;
  unsigned r = v.u + 0x7FFFu + ((v.u >> 16) & 1u);  // RNE
  return (unsigned short)(r >> 16);
}

__device__ __forceinline__ float pick4(int k, float a, float b, float c, float d) {
  return (k == 0) ? a : ((k == 1) ? b : ((k == 2) ? c : d));
}

// ---------- device-coherent (sc0 sc1) data plane for cross-WG data ----------
__device__ __forceinline__ float cloadf(const float* p) {
  return __hip_atomic_load(p, __ATOMIC_RELAXED, __HIP_MEMORY_SCOPE_AGENT);
}
__device__ __forceinline__ void cstoref(float* p, float v) {
  __hip_atomic_store(p, v, __ATOMIC_RELAXED, __HIP_MEMORY_SCOPE_AGENT);
}
__device__ __forceinline__ void cstoreu(unsigned* p, unsigned v) {
  __hip_atomic_store(p, v, __ATOMIC_RELAXED, __HIP_MEMORY_SCOPE_AGENT);
}
// pack bf16 shadow pairs: even lane stores (v, neighbor v) as one u32
__device__ __forceinline__ void cstore_sh(unsigned short* base, size_t idx, float v, int lane) {
  float vo = __shfl_xor(v, 1);
  if (!(lane & 1)) {
    unsigned pk = (unsigned)f2bf(v) | ((unsigned)f2bf(vo) << 16);
    cstoreu((unsigned*)(base + idx), pk);
  }
}

// bulk coherent stage (activations): rows x (C4*4) bf16 -> LDS, whole WG
template <int C4>
__device__ __forceinline__ void stage_coh(unsigned short* lds, int ldsStride, int ldsColOff,
                                          const unsigned short* src, int srcStride, int rows) {
  const int total = rows * C4;
  for (int i = threadIdx.x; i < total; i += WGS) {
    int r = i / C4, q = (i % C4) * 4;
    unsigned long long v = __hip_atomic_load(
        (const unsigned long long*)(src + (size_t)r * srcStride + q),
        __ATOMIC_RELAXED, __HIP_MEMORY_SCOPE_AGENT);
    *(unsigned long long*)(lds + (size_t)r * ldsStride + ldsColOff + q) = v;
  }
}

// bulk plain stage (weights; static, published once via gbar_init fences)
template <int C4>
__device__ __forceinline__ void stage_pln(unsigned short* lds, int ldsStride,
                                          const unsigned short* src, int srcStride, int rows) {
  const int total = rows * C4;
  for (int i = threadIdx.x; i < total; i += WGS) {
    int r = i / C4, q = (i % C4) * 4;
    *(unsigned long long*)(lds + (size_t)r * ldsStride + q) =
        *(const unsigned long long*)(src + (size_t)r * srcStride + q);
  }
}

// cell W chunk stage: 128 LDS rows, gate-interleaved: LDS row rr -> global row
// n = (rr>>5)*H + ng*32 + (rr&31); cols [scol, scol+CK)
template <int CK>
__device__ __forceinline__ void stage_cw(unsigned short* lds, const unsigned short* wsrc,
                                         int wstr, int scol, int ng) {
  constexpr int C4 = CK >> 2;
  const int total = 128 * C4;
  for (int i = threadIdx.x; i < total; i += WGS) {
    const int rr = i / C4, q = (i % C4) * 4;
    const int n = (rr >> 5) * H_ + ng * 32 + (rr & 31);
    *(unsigned long long*)(lds + (size_t)rr * LSTR_W + q) =
        *(const unsigned long long*)(wsrc + (size_t)n * wstr + scol + q);
  }
}

// ---- fence-free device barrier (proven at 256 WGs in earlier rounds)
__device__ __forceinline__ void gbar_fast(GBar* b) {
  __syncthreads();
  if (threadIdx.x == 0) {
    unsigned g = __hip_atomic_load(&b->gen[0], __ATOMIC_RELAXED, __HIP_MEMORY_SCOPE_AGENT);
    int leaf = blockIdx.x >> 3;  // 32 leaves x 8 WGs
    unsigned a = __hip_atomic_fetch_add(&b->leaf[leaf][0], 1u, __ATOMIC_RELAXED,
                                        __HIP_MEMORY_SCOPE_AGENT);
    if (a == 7u) {
      unsigned r = __hip_atomic_fetch_add(&b->root[0], 1u, __ATOMIC_RELAXED,
                                          __HIP_MEMORY_SCOPE_AGENT);
      if (r == 31u) {
        for (int i = 0; i < 32; i++)
          __hip_atomic_store(&b->leaf[i][0], 0u, __ATOMIC_RELAXED, __HIP_MEMORY_SCOPE_AGENT);
        __hip_atomic_store(&b->root[0], 0u, __ATOMIC_RELAXED, __HIP_MEMORY_SCOPE_AGENT);
        __hip_atomic_store(&b->gen[0], g + 1u, __ATOMIC_RELEASE, __HIP_MEMORY_SCOPE_AGENT);
      }
    }
    while (__hip_atomic_load(&b->gen[0], __ATOMIC_RELAXED, __HIP_MEMORY_SCOPE_AGENT) == g)
      __builtin_amdgcn_s_sleep(1);
    asm volatile("" ::: "memory");
  }
  __syncthreads();
}

// ---- full-fence barrier: ONCE after init (weights are plain stores)
__device__ __forceinline__ void gbar_init(GBar* b) {
  __syncthreads();
  if (threadIdx.x == 0) {
    __builtin_amdgcn_fence(__ATOMIC_RELEASE, "agent");
    unsigned g = __hip_atomic_load(&b->gen[0], __ATOMIC_RELAXED, __HIP_MEMORY_SCOPE_AGENT);
    int leaf = blockIdx.x >> 3;
    unsigned a = __hip_atomic_fetch_add(&b->leaf[leaf][0], 1u, __ATOMIC_RELAXED,
                                        __HIP_MEMORY_SCOPE_AGENT);
    if (a == 7u) {
      unsigned r = __hip_atomic_fetch_add(&b->root[0], 1u, __ATOMIC_RELAXED,
                                          __HIP_MEMORY_SCOPE_AGENT);
      if (r == 31u) {
        for (int i = 0; i < 32; i++)
          __hip_atomic_store(&b->leaf[i][0], 0u, __ATOMIC_RELAXED, __HIP_MEMORY_SCOPE_AGENT);
        __hip_atomic_store(&b->root[0], 0u, __ATOMIC_RELAXED, __HIP_MEMORY_SCOPE_AGENT);
        __hip_atomic_store(&b->gen[0], g + 1u, __ATOMIC_RELEASE, __HIP_MEMORY_SCOPE_AGENT);
      }
    }
    while (__hip_atomic_load(&b->gen[0], __ATOMIC_RELAXED, __HIP_MEMORY_SCOPE_AGENT) == g)
      __builtin_amdgcn_s_sleep(1);
    __builtin_amdgcn_fence(__ATOMIC_ACQUIRE, "agent");
  }
  __syncthreads();
}

// ---- mog2 unit: 2 tiles (nt=ng*2, ng*2+1), K=1024, 8 waves = 2 tiles x 4 Kq.
// A(16 rows) + W(32 rows) both staged to LDS; MFMA reads only LDS.
__device__ __forceinline__ void mog2_unit(
    const unsigned short* __restrict__ A,   // [128][1024] bf16 shadow
    const unsigned short* __restrict__ W,   // [1024][1024]
    const float* __restrict__ bias,
    const float* srcF, int srcStride,
    float* dstF, unsigned short* dstS,
    int mt, int ng, unsigned short* As, unsigned short* Ws, float (*red)[4][64]) {
  const int tid = threadIdx.x, lane = tid & 63, wv = tid >> 6;
  const int l15 = lane & 15, lq = lane >> 4;
  const int t = wv >> 2, kq = wv & 3;
  float srcv[4] = {0.f, 0.f, 0.f, 0.f};
  float bn = 0.f;
  if (kq == 0) {  // epi waves hoist their operands (hide L3 latency)
    const int n = ng * 32 + t * 16 + l15;
    bn = bias[n];
#pragma unroll
    for (int j = 0; j < 4; j++)
      srcv[j] = cloadf(&srcF[(size_t)(mt * 16 + lq * 4 + j) * srcStride + n]);
  }
  stage_pln<256>(Ws, LSTR_MOG, W + (size_t)(ng * 32) * 1024, 1024, 32);
  stage_coh<256>(As, LSTR_MOG, 0, A + (size_t)(mt * 16) * 1024, 1024, 16);
  __syncthreads();
  const unsigned short* ap = As + l15 * LSTR_MOG + kq * 256 + lq * 8;
  const unsigned short* wp = Ws + (t * 16 + l15) * LSTR_MOG + kq * 256 + lq * 8;
  facc4 acc = {0.f, 0.f, 0.f, 0.f};
#pragma unroll
  for (int st = 0; st < 8; st++)
    acc = MFMA_BF16(*(const bfrag8*)(ap + st * 32), *(const bfrag8*)(wp + st * 32), acc, 0, 0, 0);
  red[wv][0][lane] = acc[0]; red[wv][1][lane] = acc[1];
  red[wv][2][lane] = acc[2]; red[wv][3][lane] = acc[3];
  __syncthreads();
  if (kq == 0) {
    const int n = ng * 32 + t * 16 + l15;
#pragma unroll
    for (int j = 0; j < 4; j++) {
      float d = red[t * 4 + 0][j][lane] + red[t * 4 + 1][j][lane] +
                red[t * 4 + 2][j][lane] + red[t * 4 + 3][j][lane];
      float v = 2.0f * sigf(d + bn) * srcv[j];
      const int m = mt * 16 + lq * 4 + j;
      cstoref(&dstF[(size_t)m * H_ + n], v);
      cstore_sh(dstS, (size_t)m * H_ + n, v, lane);
    }
  }
}

// ---- mog1 Q unit: single 16x16 tile, K=1024, 8-way K-split.
__device__ __forceinline__ void mog1q_unit(
    const unsigned short* __restrict__ A,   // h1 shadow [128][1024]
    const unsigned short* __restrict__ W,   // [128][1024]
    const float* __restrict__ bias,
    const float* srcF, int srcStride,
    float* dstF, unsigned short* dstS,      // N = 128
    int mt, int nt, unsigned short* As, unsigned short* Ws, float (*red)[4][64]) {
  const int tid = threadIdx.x, lane = tid & 63, wv = tid >> 6;
  const int l15 = lane & 15, lq = lane >> 4;
  float srcv[4] = {0.f, 0.f, 0.f, 0.f};
  float bn = 0.f;
  if (wv == 0) {
    const int n = nt * 16 + l15;
    bn = bias[n];
#pragma unroll
    for (int j = 0; j < 4; j++)
      srcv[j] = cloadf(&srcF[(size_t)(mt * 16 + lq * 4 + j) * srcStride + n]);
  }
  stage_pln<256>(Ws, LSTR_MOG, W + (size_t)(nt * 16) * 1024, 1024, 16);
  stage_coh<256>(As, LSTR_MOG, 0, A + (size_t)(mt * 16) * 1024, 1024, 16);
  __syncthreads();
  const unsigned short* ap = As + l15 * LSTR_MOG + wv * 128 + lq * 8;
  const unsigned short* wp = Ws + l15 * LSTR_MOG + wv * 128 + lq * 8;
  facc4 acc = {0.f, 0.f, 0.f, 0.f};
#pragma unroll
  for (int st = 0; st < 4; st++)
    acc = MFMA_BF16(*(const bfrag8*)(ap + st * 32), *(const bfrag8*)(wp + st * 32), acc, 0, 0, 0);
  red[wv][0][lane] = acc[0]; red[wv][1][lane] = acc[1];
  red[wv][2][lane] = acc[2]; red[wv][3][lane] = acc[3];
  __syncthreads();
  if (wv == 0) {
    const int n = nt * 16 + l15;
#pragma unroll
    for (int j = 0; j < 4; j++) {
      float d = 0.f;
#pragma unroll
      for (int w = 0; w < 8; w++) d += red[w][j][lane];
      float v = 2.0f * sigf(d + bn) * srcv[j];
      const int m = mt * 16 + lq * 4 + j;
      cstoref(&dstF[(size_t)m * I_ + n], v);
      cstore_sh(dstS, (size_t)m * I_ + n, v, lane);
    }
  }
}

// ---- mog1 R unit: nt-block x all 8 mt, K=128 full per wave, wave-local epi.
__device__ __forceinline__ void mog1r_unit(
    const unsigned short* __restrict__ A,   // x1s [128][128]
    const unsigned short* __restrict__ W,   // [1024][128]
    const float* __restrict__ bias,
    float* hF, unsigned short* hS,          // src == dst (in-place h update)
    int nt, unsigned short* As, unsigned short* Ws) {
  const int tid = threadIdx.x, lane = tid & 63, wv = tid >> 6;
  const int l15 = lane & 15, lq = lane >> 4;
  const int n = nt * 16 + l15;
  const int mbase = wv * 16;
  float srcv[4];
#pragma unroll
  for (int j = 0; j < 4; j++)
    srcv[j] = cloadf(&hF[(size_t)(mbase + lq * 4 + j) * H_ + n]);
  const float bn = bias[n];
  stage_pln<32>(Ws, LSTR_R1, W + (size_t)(nt * 16) * 128, 128, 16);
  stage_coh<32>(As, LSTR_R1, 0, A, 128, 128);
  __syncthreads();
  const unsigned short* ap = As + (mbase + l15) * LSTR_R1 + lq * 8;
  const unsigned short* wp = Ws + l15 * LSTR_R1 + lq * 8;
  facc4 acc = {0.f, 0.f, 0.f, 0.f};
#pragma unroll
  for (int st = 0; st < 4; st++)
    acc = MFMA_BF16(*(const bfrag8*)(ap + st * 32), *(const bfrag8*)(wp + st * 32), acc, 0, 0, 0);
#pragma unroll
  for (int j = 0; j < 4; j++) {
    float v = 2.0f * sigf(acc[j] + bn) * srcv[j];
    const int m = mbase + lq * 4 + j;
    cstoref(&hF[(size_t)m * H_ + n], v);
    cstore_sh(hS, (size_t)m * H_ + n, v, lane);
  }
}

// ---- LSTM cell: WG = (mt, ng). Wave wv owns 4 H-cols x 4 gates (16 W rows,
// gate-interleaved) -> epilogue is wave-local via 3 shfl_xor. W streamed in
// 256-k LDS chunks (acc carried in regs); A staged once.
template <int CELL>
__device__ __forceinline__ void cell_unit(
    const unsigned short* __restrict__ Xs,
    const unsigned short* __restrict__ Hs,
    const unsigned short* __restrict__ Wih,
    const unsigned short* __restrict__ Whh,
    const float* __restrict__ bsum,
    float* cst, float* hF, unsigned short* hS,
    int mt, int ng, unsigned short* As, unsigned short* Ws) {
  constexpr int KX = (CELL == 1) ? 128 : 1024;
  constexpr int LSTRA = (CELL == 1) ? LSTR_C1 : LSTR_C2;
  constexpr int NCH = (CELL == 1) ? 5 : 8;
  const int tid = threadIdx.x, lane = tid & 63, wv = tid >> 6;
  const int l15 = lane & 15, lq = lane >> 4;
  const int g = l15 >> 2, cc = l15 & 3;
  const int col = ng * 32 + wv * 4 + cc;
  // hoist c + biases (hide L3 latency under staging/MFMA)
  float coldv[4];
#pragma unroll
  for (int j = 0; j < 4; j++)
    coldv[j] = cloadf(&cst[(size_t)(mt * 16 + lq * 4 + j) * H_ + col]);
  const float bi = bsum[col], bf2 = bsum[H_ + col], bg2 = bsum[2 * H_ + col], bo = bsum[3 * H_ + col];

  stage_coh<KX / 4>(As, LSTRA, 0, Xs + (size_t)(mt * 16) * KX, KX, 16);
  stage_coh<256>(As, LSTRA, KX, Hs + (size_t)(mt * 16) * 1024, 1024, 16);

  const int rrW = (g << 5) + (wv << 2) + cc;  // gate-interleaved W LDS row
  facc4 acc = {0.f, 0.f, 0.f, 0.f};
#pragma unroll
  for (int c = 0; c < NCH; c++) {
    int acol, nst;
    if (CELL == 1) {
      if (c == 0) { stage_cw<128>(Ws, Wih, 128, 0, ng); acol = 0; nst = 4; }
      else { stage_cw<256>(Ws, Whh, 1024, (c - 1) * 256, ng); acol = 128 + (c - 1) * 256; nst = 8; }
    } else {
      if (c < 4) { stage_cw<256>(Ws, Wih, 1024, c * 256, ng); }
      else       { stage_cw<256>(Ws, Whh, 1024, (c - 4) * 256, ng); }
      acol = c * 256; nst = 8;
    }
    __syncthreads();
    const unsigned short* ap = As + l15 * LSTRA + acol + lq * 8;
    const unsigned short* wp = Ws + rrW * LSTR_W + lq * 8;
#pragma unroll
    for (int st = 0; st < 8; st++) {
      if (st < nst)
        acc = MFMA_BF16(*(const bfrag8*)(ap + st * 32), *(const bfrag8*)(wp + st * 32), acc, 0, 0, 0);
    }
    __syncthreads();
  }
  // wave-local epilogue: gather the 4 gates across l15 bits 2..3
#pragma unroll
  for (int j = 0; j < 4; j++) {
    float d0 = acc[j];
    float d1 = __shfl_xor(d0, 4), d2 = __shfl_xor(d0, 8), d3 = __shfl_xor(d0, 12);
    float pi = pick4(g, d0, d1, d2, d3);          // gate 0: k = g^0
    float pf = pick4(g ^ 1, d0, d1, d2, d3);      // gate 1
    float pg = pick4(g ^ 2, d0, d1, d2, d3);      // gate 2
    float po = pick4(g ^ 3, d0, d1, d2, d3);      // gate 3
    float iv = sigf(pi + bi);
    float fv = sigf(pf + bf2);
    float gv = tanhf(pg + bg2);
    float ov = sigf(po + bo);
    float cn = fv * coldv[j] + iv * gv;
    float hn = ov * tanhf(cn);
    const int m = mt * 16 + lq * 4 + j;
    const size_t idx = (size_t)m * H_ + col;
    float hno = __shfl_xor(hn, 1);  // neighbor col (cc^1), same gate
    if (g == 0) {
      cstoref(&cst[idx], cn);
      cstoref(&hF[idx], hn);
      if (!(cc & 1)) {
        unsigned pk = (unsigned)f2bf(hn) | ((unsigned)f2bf(hno) << 16);
        cstoreu((unsigned*)(hS + idx), pk);
      }
    }
  }
}

__global__ __launch_bounds__(WGS, 1) void moglstm_kernel(
    const float* __restrict__ in_seq,
    const float* __restrict__ c1Q, const float* __restrict__ c1Qb,
    const float* __restrict__ c1R, const float* __restrict__ c1Rb,
    const float* __restrict__ c1Wih, const float* __restrict__ c1Whh,
    const float* __restrict__ c1bih, const float* __restrict__ c1bhh,
    const float* __restrict__ c2Q, const float* __restrict__ c2Qb,
    const float* __restrict__ c2R, const float* __restrict__ c2Rb,
    const float* __restrict__ c2Wih, const float* __restrict__ c2Whh,
    const float* __restrict__ c2bih, const float* __restrict__ c2bhh,
    const float* __restrict__ linW, const float* __restrict__ linb,
    char* ws, float* __restrict__ out) {
  extern __shared__ char dynlds[];
  unsigned short* As = (unsigned short*)(dynlds + A_OFF);
  unsigned short* Ws = (unsigned short*)(dynlds + W_OFF);
  float (*red)[4][64] = reinterpret_cast<float(*)[4][64]>(dynlds + RED_OFF);

  GBar* bar = (GBar*)(ws + OFF_BAR);
  float* h1f0 = (float*)(ws + OFF_H1F);
  float* h1f1 = h1f0 + (size_t)B_ * H_;
  float* h2f0 = (float*)(ws + OFF_H2F);
  float* h2f1 = h2f0 + (size_t)B_ * H_;
  float* c1f = (float*)(ws + OFF_C1);
  float* c2f = (float*)(ws + OFF_C2);
  float* x1f = (float*)(ws + OFF_X1F);
  float* x2f = (float*)(ws + OFF_X2F);
  unsigned short* h1s0 = (unsigned short*)(ws + OFF_H1S);
  unsigned short* h1s1 = h1s0 + (size_t)B_ * H_;
  unsigned short* h2s0 = (unsigned short*)(ws + OFF_H2S);
  unsigned short* h2s1 = h2s0 + (size_t)B_ * H_;
  unsigned short* x1s = (unsigned short*)(ws + OFF_X1S);
  unsigned short* x2s = (unsigned short*)(ws + OFF_X2S);
  float* bs1 = (float*)(ws + OFF_BS1);
  float* bs2 = (float*)(ws + OFF_BS2);
  unsigned short* wq1 = (unsigned short*)(ws + OFF_WQ1);
  unsigned short* wr1 = (unsigned short*)(ws + OFF_WR1);
  unsigned short* wih1 = (unsigned short*)(ws + OFF_WIH1);
  unsigned short* whh1 = (unsigned short*)(ws + OFF_WHH1);
  unsigned short* wq2 = (unsigned short*)(ws + OFF_WQ2);
  unsigned short* wr2 = (unsigned short*)(ws + OFF_WR2);
  unsigned short* wih2 = (unsigned short*)(ws + OFF_WIH2);
  unsigned short* whh2 = (unsigned short*)(ws + OFF_WHH2);

  const int wg = blockIdx.x;

  // ---- init: fp32 -> bf16 weight conversion (plain stores) + bias sums
  {
    size_t gt = (size_t)wg * WGS + threadIdx.x;
    const size_t gs = (size_t)NWG * WGS;
    const float* srcs[8] = {c1Q, c1R, c1Wih, c1Whh, c2Q, c2R, c2Wih, c2Whh};
    unsigned short* dsts[8] = {wq1, wr1, wih1, whh1, wq2, wr2, wih2, whh2};
    const size_t cnts[8] = {3ull * I_ * H_, 2ull * H_ * I_, (size_t)G_ * I_,
                            (size_t)G_ * H_, 3ull * H_ * H_, 2ull * H_ * H_,
                            (size_t)G_ * H_, (size_t)G_ * H_};
    for (int a = 0; a < 8; a++)
      for (size_t i = gt; i < cnts[a]; i += gs) dsts[a][i] = f2bf(srcs[a][i]);
    for (size_t i = gt; i < (size_t)G_; i += gs) bs1[i] = c1bih[i] + c1bhh[i];
    for (size_t i = gt; i < (size_t)G_; i += gs) bs2[i] = c2bih[i] + c2bhh[i];
  }
  gbar_init(bar);  // full fences ONCE: publish plain-stored weights

  // phase p: layer-1 step p and layer-2 step p-1 concurrently; 6 phases/iter.
  // mog2: all 256 WGs as (mt = wg>>5, ng = wg&31).  wg&7 = ng&7 -> the 8 WGs
  // sharing a W slice land on one XCD (W slices L2-resident per XCD).
  // mog1 rides along on WGs 192..255. cells: all WGs, both cells serial.
  for (int p = 0; p <= T_; ++p) {
    const int q = p & 1;
    const int q2 = 1 - q;
    const bool doL1 = (p < T_);
    const bool doL2 = (p > 0);
    float* h1q = q ? h1f1 : h1f0;
    float* h1o = q ? h1f0 : h1f1;
    unsigned short* h1sq = q ? h1s1 : h1s0;
    unsigned short* h1so = q ? h1s0 : h1s1;
    float* h2q2 = q2 ? h2f1 : h2f0;
    float* h2o = q ? h2f1 : h2f0;
    unsigned short* h2sq2 = q2 ? h2s1 : h2s0;
    unsigned short* h2so = q ? h2s1 : h2s0;

    const int mt = wg >> 5, ng = wg & 31;

    for (int s = 0; s < 6; ++s) {
      if (s == 1 || s == 3) {  // R rounds
        if (doL2) {
          const unsigned short* W = (s == 1) ? wr2 : wr2 + 1ull * H_ * H_;
          const float* bias = (s == 1) ? c2Rb : c2Rb + H_;
          mog2_unit(x2s, W, bias, h2q2, H_, h2q2, h2sq2, mt, ng, As, Ws, red);
        }
        if (doL1 && wg >= 192) {
          const unsigned short* W = (s == 1) ? wr1 : wr1 + 1ull * H_ * I_;
          const float* bias = (s == 1) ? c1Rb : c1Rb + H_;
          mog1r_unit(x1s, W, bias, h1q, h1sq, wg - 192, As, Ws);
        }
      } else if (s < 5) {      // Q rounds: r = 0,1,2
        const int r = s >> 1;
        if (doL2) {
          mog2_unit(h2sq2, wq2 + (size_t)r * H_ * H_, c2Qb + r * H_,
                    (r == 0) ? h1q : x2f, H_, x2f, x2s, mt, ng, As, Ws, red);
        }
        if (doL1 && wg >= 192) {
          const int w1 = wg - 192;
          const float* srcF = (r == 0) ? (in_seq + (size_t)p * I_) : x1f;
          const int sstr = (r == 0) ? T_ * I_ : I_;
          mog1q_unit(h1sq, wq1 + (size_t)r * I_ * H_, c1Qb + r * I_, srcF, sstr,
                     x1f, x1s, w1 & 7, w1 >> 3, As, Ws, red);
        }
      } else {                 // s == 5: both LSTM cells, serial per WG
        if (doL1) cell_unit<1>(x1s, h1sq, wih1, whh1, bs1, c1f, h1o, h1so, mt, ng, As, Ws);
        if (doL2) cell_unit<2>(x2s, h2sq2, wih2, whh2, bs2, c2f, h2o, h2so, mt, ng, As, Ws);
      }
      gbar_fast(bar);
    }
  }

  // ---- final linear: out[b] = dot(h2_final[b,:], linW) + linb (parity 0)
  if (wg == 0) {
    float* rf = (float*)dynlds;
    const int tid = threadIdx.x;
    const int b = tid >> 2, qq = tid & 3;
    const float* row = h2f0 + (size_t)b * H_ + qq * 256;
    const float* w = linW + qq * 256;
    float s = 0.f;
    for (int k = 0; k < 256; k++) s += cloadf(&row[k]) * w[k];
    rf[tid] = s;
    __syncthreads();
    if (tid < B_)
      out[tid] = rf[tid * 4] + rf[tid * 4 + 1] + rf[tid * 4 + 2] + rf[tid * 4 + 3] + linb[0];
  }
}

extern "C" void kernel_launch(void* const* d_in, const int* in_sizes, int n_in,
                              void* d_out, int out_size, void* d_ws, size_t ws_size,
                              hipStream_t stream) {
  const float* in_seq = (const float*)d_in[0];
  const float* c1Q = (const float*)d_in[1];
  const float* c1Qb = (const float*)d_in[2];
  const float* c1R = (const float*)d_in[3];
  const float* c1Rb = (const float*)d_in[4];
  const float* c1Wih = (const float*)d_in[5];
  const float* c1Whh = (const float*)d_in[6];
  const float* c1bih = (const float*)d_in[7];
  const float* c1bhh = (const float*)d_in[8];
  const float* c2Q = (const float*)d_in[9];
  const float* c2Qb = (const float*)d_in[10];
  const float* c2R = (const float*)d_in[11];
  const float* c2Rb = (const float*)d_in[12];
  const float* c2Wih = (const float*)d_in[13];
  const float* c2Whh = (const float*)d_in[14];
  const float* c2bih = (const float*)d_in[15];
  const float* c2bhh = (const float*)d_in[16];
  const float* linW = (const float*)d_in[17];
  const float* linb = (const float*)d_in[18];

  static_assert(DYN_LDS == 141568, "lds layout");
  hipFuncSetAttribute((const void*)moglstm_kernel,
                      hipFuncAttributeMaxDynamicSharedMemorySize, (int)DYN_LDS);
  hipMemsetAsync(d_ws, 0, ZERO_BYTES, stream);
  moglstm_kernel<<<dim3(NWG), dim3(WGS), DYN_LDS, stream>>>(
      in_seq, c1Q, c1Qb, c1R, c1Rb, c1Wih, c1Whh, c1bih, c1bhh,
      c2Q, c2Qb, c2R, c2Rb, c2Wih, c2Whh, c2bih, c2bhh,
      linW, linb, (char*)d_ws, (float*)d_out);
}

// Round 4
// 68219.885 us; speedup vs baseline: 1.3120x; 1.3120x over previous
//
#include <hip/hip_runtime.h>

#define NWG 256
#define WGS 512

typedef __attribute__((ext_vector_type(4))) float facc4;
typedef __attribute__((ext_vector_type(8))) short bfrag8;

#define MFMA_BF16 __builtin_amdgcn_mfma_f32_16x16x32_bf16

constexpr int B_ = 128, T_ = 512, I_ = 128, H_ = 1024;
constexpr int G_ = 4 * H_;  // 4096

// ---------------- workspace layout (bytes) ----------------
constexpr size_t OFF_BAR  = 0;        // 8192 reserved (padded barrier lines)
constexpr size_t OFF_H1F  = 8192;
constexpr size_t OFF_H2F  = OFF_H1F + 2ull * B_ * H_ * 4;
constexpr size_t OFF_C1   = OFF_H2F + 2ull * B_ * H_ * 4;
constexpr size_t OFF_C2   = OFF_C1 + (size_t)B_ * H_ * 4;
constexpr size_t OFF_X1F  = OFF_C2 + (size_t)B_ * H_ * 4;
constexpr size_t OFF_X2F  = OFF_X1F + (size_t)B_ * I_ * 4;
constexpr size_t OFF_H1S  = OFF_X2F + (size_t)B_ * H_ * 4;
constexpr size_t OFF_H2S  = OFF_H1S + 2ull * B_ * H_ * 2;
constexpr size_t OFF_X1S  = OFF_H2S + 2ull * B_ * H_ * 2;
constexpr size_t OFF_X2S  = OFF_X1S + (size_t)B_ * I_ * 2;
constexpr size_t OFF_BS1  = OFF_X2S + (size_t)B_ * H_ * 2;
constexpr size_t OFF_BS2  = OFF_BS1 + (size_t)G_ * 4;
constexpr size_t ZERO_BYTES = OFF_BS2 + (size_t)G_ * 4;
// bf16 weights (converted in-kernel each launch), L2-resident afterwards
constexpr size_t OFF_WQ1  = ZERO_BYTES;                         // 3*I*H
constexpr size_t OFF_WR1  = OFF_WQ1 + 3ull * I_ * H_ * 2;       // 2*H*I
constexpr size_t OFF_WIH1 = OFF_WR1 + 2ull * H_ * I_ * 2;       // G*I
constexpr size_t OFF_WHH1 = OFF_WIH1 + (size_t)G_ * I_ * 2;     // G*H
constexpr size_t OFF_WQ2  = OFF_WHH1 + (size_t)G_ * H_ * 2;     // 3*H*H
constexpr size_t OFF_WR2  = OFF_WQ2 + 3ull * H_ * H_ * 2;       // 2*H*H
constexpr size_t OFF_WIH2 = OFF_WR2 + 2ull * H_ * H_ * 2;       // G*H
constexpr size_t OFF_WHH2 = OFF_WIH2 + (size_t)G_ * H_ * 2;     // G*H

// ---------------- dynamic LDS ----------------
// A-staging (worst: cell2 16 x 2056 els) + red for cell gate exchange.
// All row strides == 16 B (mod 128 B) -> 16-row b128 reads are 2-way (free).
constexpr size_t A_OFF   = 0;                    // 16*2056*2 = 65792
constexpr size_t RED_OFF = 65792;                // 8*2*4*64*4 = 16384
constexpr size_t DYN_LDS = RED_OFF + 16384;      // 82176

struct GBar {
  unsigned leaf[32][32];  // one counter per 128B line
  unsigned root[32];
  unsigned gen[32];
};

__device__ __forceinline__ float sigf(float x) { return 1.0f / (1.0f + __expf(-x)); }

__device__ __forceinline__ unsigned short f2bf(float f) {
  union { float f; unsigned u; } v; v.f = f;
  unsigned r = v.u + 0x7FFFu + ((v.u >> 16) & 1u);  // RNE
  return (unsigned short)(r >> 16);
}

// ---------- device-coherent (sc0 sc1) data plane for cross-WG data ----------
__device__ __forceinline__ float cloadf(const float* p) {
  return __hip_atomic_load(p, __ATOMIC_RELAXED, __HIP_MEMORY_SCOPE_AGENT);
}
__device__ __forceinline__ void cstoref(float* p, float v) {
  __hip_atomic_store(p, v, __ATOMIC_RELAXED, __HIP_MEMORY_SCOPE_AGENT);
}
__device__ __forceinline__ void cstoreu(unsigned* p, unsigned v) {
  __hip_atomic_store(p, v, __ATOMIC_RELAXED, __HIP_MEMORY_SCOPE_AGENT);
}
// pack bf16 shadow pairs: even lane stores (v, neighbor v) as one u32
__device__ __forceinline__ void cstore_sh(unsigned short* base, size_t idx, float v, int lane) {
  float vo = __shfl_xor(v, 1);
  if (!(lane & 1)) {
    unsigned pk = (unsigned)f2bf(v) | ((unsigned)f2bf(vo) << 16);
    cstoreu((unsigned*)(base + idx), pk);
  }
}

// bulk coherent stage (activations): rows x (C4*4) bf16 -> LDS, whole WG
template <int C4>
__device__ __forceinline__ void stage_coh(unsigned short* lds, int ldsStride, int ldsColOff,
                                          const unsigned short* src, int srcStride, int rows) {
  const int total = rows * C4;
  for (int i = threadIdx.x; i < total; i += WGS) {
    int r = i / C4, q = (i % C4) * 4;
    unsigned long long v = __hip_atomic_load(
        (const unsigned long long*)(src + (size_t)r * srcStride + q),
        __ATOMIC_RELAXED, __HIP_MEMORY_SCOPE_AGENT);
    *(unsigned long long*)(lds + (size_t)r * ldsStride + ldsColOff + q) = v;
  }
}

// ---- fence-free device barrier (proven at 256 WGs in round 0)
__device__ __forceinline__ void gbar_fast(GBar* b) {
  __syncthreads();
  if (threadIdx.x == 0) {
    unsigned g = __hip_atomic_load(&b->gen[0], __ATOMIC_RELAXED, __HIP_MEMORY_SCOPE_AGENT);
    int leaf = blockIdx.x >> 3;  // 32 leaves x 8 WGs
    unsigned a = __hip_atomic_fetch_add(&b->leaf[leaf][0], 1u, __ATOMIC_RELAXED,
                                        __HIP_MEMORY_SCOPE_AGENT);
    if (a == 7u) {
      unsigned r = __hip_atomic_fetch_add(&b->root[0], 1u, __ATOMIC_RELAXED,
                                          __HIP_MEMORY_SCOPE_AGENT);
      if (r == 31u) {
        for (int i = 0; i < 32; i++)
          __hip_atomic_store(&b->leaf[i][0], 0u, __ATOMIC_RELAXED, __HIP_MEMORY_SCOPE_AGENT);
        __hip_atomic_store(&b->root[0], 0u, __ATOMIC_RELAXED, __HIP_MEMORY_SCOPE_AGENT);
        __hip_atomic_store(&b->gen[0], g + 1u, __ATOMIC_RELEASE, __HIP_MEMORY_SCOPE_AGENT);
      }
    }
    while (__hip_atomic_load(&b->gen[0], __ATOMIC_RELAXED, __HIP_MEMORY_SCOPE_AGENT) == g)
      __builtin_amdgcn_s_sleep(1);
    asm volatile("" ::: "memory");
  }
  __syncthreads();
}

// ---- full-fence barrier: ONCE after init (weights are plain stores)
__device__ __forceinline__ void gbar_init(GBar* b) {
  __syncthreads();
  if (threadIdx.x == 0) {
    __builtin_amdgcn_fence(__ATOMIC_RELEASE, "agent");
    unsigned g = __hip_atomic_load(&b->gen[0], __ATOMIC_RELAXED, __HIP_MEMORY_SCOPE_AGENT);
    int leaf = blockIdx.x >> 3;
    unsigned a = __hip_atomic_fetch_add(&b->leaf[leaf][0], 1u, __ATOMIC_RELAXED,
                                        __HIP_MEMORY_SCOPE_AGENT);
    if (a == 7u) {
      unsigned r = __hip_atomic_fetch_add(&b->root[0], 1u, __ATOMIC_RELAXED,
                                          __HIP_MEMORY_SCOPE_AGENT);
      if (r == 31u) {
        for (int i = 0; i < 32; i++)
          __hip_atomic_store(&b->leaf[i][0], 0u, __ATOMIC_RELAXED, __HIP_MEMORY_SCOPE_AGENT);
        __hip_atomic_store(&b->root[0], 0u, __ATOMIC_RELAXED, __HIP_MEMORY_SCOPE_AGENT);
        __hip_atomic_store(&b->gen[0], g + 1u, __ATOMIC_RELEASE, __HIP_MEMORY_SCOPE_AGENT);
      }
    }
    while (__hip_atomic_load(&b->gen[0], __ATOMIC_RELAXED, __HIP_MEMORY_SCOPE_AGENT) == g)
      __builtin_amdgcn_s_sleep(1);
    __builtin_amdgcn_fence(__ATOMIC_ACQUIRE, "agent");
  }
  __syncthreads();
}

// ---- wave-local mog unit: wave wv computes ONE 16x16 tile (nt = ntBase+wv)
// with FULL K. No K-split, no cross-wave reduce, one __syncthreads.
// A: 16 rows staged coherent (once per WG); W: per-lane cached reads
// (16 rows x K x 2B = <=32 KB per wave; round-0-proven regime).
// acc[j] -> (m = mt*16 + lq*4 + j, n = nt*16 + l15)  [round-0-verified layout]
template <int K>
__device__ __forceinline__ void mog_wl(
    const unsigned short* __restrict__ A,   // bf16 shadow, row stride K
    const unsigned short* __restrict__ W,   // N rows x K, plain-cached
    const float* __restrict__ bias,
    const float* srcF, int srcStride,
    float* dstF, unsigned short* dstS, int N,
    int mt, int ntBase, unsigned short* As) {
  const int tid = threadIdx.x, lane = tid & 63, wv = tid >> 6;
  const int l15 = lane & 15, lq = lane >> 4;
  const int nt = ntBase + wv, n = nt * 16 + l15;
  constexpr int LSTR = K + 8;
  // hoist epilogue coherent operands (hide L3 latency under staging+MFMA)
  float srcv[4];
#pragma unroll
  for (int j = 0; j < 4; j++)
    srcv[j] = cloadf(&srcF[(size_t)(mt * 16 + lq * 4 + j) * srcStride + n]);
  const float bn = bias[n];

  stage_coh<K / 4>(As, LSTR, 0, A + (size_t)(mt * 16) * K, K, 16);
  __syncthreads();

  const unsigned short* ap = As + l15 * LSTR + lq * 8;
  const unsigned short* wp = W + (size_t)n * K + lq * 8;
  facc4 acc = {0.f, 0.f, 0.f, 0.f};
#pragma unroll 8
  for (int k = 0; k < K; k += 32)
    acc = MFMA_BF16(*(const bfrag8*)(ap + k), *(const bfrag8*)(wp + k), acc, 0, 0, 0);
#pragma unroll
  for (int j = 0; j < 4; j++) {
    float v = 2.0f * sigf(acc[j] + bn) * srcv[j];
    const int m = mt * 16 + lq * 4 + j;
    cstoref(&dstF[(size_t)m * N + n], v);
    cstore_sh(dstS, (size_t)m * N + n, v, lane);
  }
  // no trailing sync: gbar_fast's leading __syncthreads protects As reuse
}

// ---- LSTM cell unit: WG = (mt, nb<16) covering 16 rows x 64 H-cols.
// 8 waves = 4 gates x 2 col-halves; wave computes 2 tiles x full K.
// Gate exchange via LDS red; epilogue on g==0 waves. A staged once (coh);
// W per-lane cached (<=128 KB/wave, nb->XCD-stable so L2-resident).
template <int CELL>
__device__ __forceinline__ void cell_wl(
    const unsigned short* __restrict__ Xs,
    const unsigned short* __restrict__ Hs,
    const unsigned short* __restrict__ Wih,
    const unsigned short* __restrict__ Whh,
    const float* __restrict__ bsum,
    float* cst, float* hF, unsigned short* hS,
    int mt, int nb, unsigned short* As, float (*red)[2][4][64]) {
  constexpr int KX = (CELL == 1) ? 128 : 1024;
  constexpr int LSTR = KX + 1024 + 8;
  const int tid = threadIdx.x, lane = tid & 63, wv = tid >> 6;
  const int l15 = lane & 15, lq = lane >> 4;
  const int g = wv >> 1, nh = wv & 1;
  const int n0 = nb * 64 + nh * 32 + l15;  // tile 0 col
  const int n1 = n0 + 16;                  // tile 1 col

  float cold[2][4];
  float bsv[2][4];
  if (g == 0) {  // epilogue waves hoist c + biases
#pragma unroll
    for (int j = 0; j < 4; j++) {
      cold[0][j] = cloadf(&cst[(size_t)(mt * 16 + lq * 4 + j) * H_ + n0]);
      cold[1][j] = cloadf(&cst[(size_t)(mt * 16 + lq * 4 + j) * H_ + n1]);
    }
#pragma unroll
    for (int gg = 0; gg < 4; gg++) {
      bsv[0][gg] = bsum[gg * H_ + n0];
      bsv[1][gg] = bsum[gg * H_ + n1];
    }
  }

  stage_coh<KX / 4>(As, LSTR, 0, Xs + (size_t)(mt * 16) * KX, KX, 16);
  stage_coh<256>(As, LSTR, KX, Hs + (size_t)(mt * 16) * 1024, 1024, 16);
  __syncthreads();

  const unsigned short* ap = As + l15 * LSTR + lq * 8;
  const int wr0 = g * H_ + nb * 64 + nh * 32 + l15;
  const unsigned short* wi0 = Wih + (size_t)wr0 * KX + lq * 8;
  const unsigned short* wi1 = wi0 + (size_t)16 * KX;
  const unsigned short* wh0 = Whh + (size_t)wr0 * 1024 + lq * 8;
  const unsigned short* wh1 = wh0 + (size_t)16 * 1024;
  facc4 a0 = {0.f, 0.f, 0.f, 0.f}, a1 = {0.f, 0.f, 0.f, 0.f};
#pragma unroll 4
  for (int k = 0; k < KX; k += 32) {
    bfrag8 af = *(const bfrag8*)(ap + k);
    a0 = MFMA_BF16(af, *(const bfrag8*)(wi0 + k), a0, 0, 0, 0);
    a1 = MFMA_BF16(af, *(const bfrag8*)(wi1 + k), a1, 0, 0, 0);
  }
#pragma unroll 4
  for (int k = 0; k < 1024; k += 32) {
    bfrag8 af = *(const bfrag8*)(ap + KX + k);
    a0 = MFMA_BF16(af, *(const bfrag8*)(wh0 + k), a0, 0, 0, 0);
    a1 = MFMA_BF16(af, *(const bfrag8*)(wh1 + k), a1, 0, 0, 0);
  }
#pragma unroll
  for (int j = 0; j < 4; j++) { red[wv][0][j][lane] = a0[j]; red[wv][1][j][lane] = a1[j]; }
  __syncthreads();

  if (g == 0) {
#pragma unroll
    for (int tt = 0; tt < 2; tt++) {
      const int n = (tt == 0) ? n0 : n1;
#pragma unroll
      for (int j = 0; j < 4; j++) {
        float di = red[0 * 2 + nh][tt][j][lane];
        float df = red[1 * 2 + nh][tt][j][lane];
        float dg = red[2 * 2 + nh][tt][j][lane];
        float dd = red[3 * 2 + nh][tt][j][lane];
        float iv = sigf(di + bsv[tt][0]);
        float fv = sigf(df + bsv[tt][1]);
        float gv = tanhf(dg + bsv[tt][2]);
        float ov = sigf(dd + bsv[tt][3]);
        float cn = fv * cold[tt][j] + iv * gv;
        float hn = ov * tanhf(cn);
        const int m = mt * 16 + lq * 4 + j;
        const size_t idx = (size_t)m * H_ + n;
        cstoref(&cst[idx], cn);
        cstoref(&hF[idx], hn);
        cstore_sh(hS, idx, hn, lane);
      }
    }
  }
}

__global__ __launch_bounds__(WGS, 1) void moglstm_kernel(
    const float* __restrict__ in_seq,
    const float* __restrict__ c1Q, const float* __restrict__ c1Qb,
    const float* __restrict__ c1R, const float* __restrict__ c1Rb,
    const float* __restrict__ c1Wih, const float* __restrict__ c1Whh,
    const float* __restrict__ c1bih, const float* __restrict__ c1bhh,
    const float* __restrict__ c2Q, const float* __restrict__ c2Qb,
    const float* __restrict__ c2R, const float* __restrict__ c2Rb,
    const float* __restrict__ c2Wih, const float* __restrict__ c2Whh,
    const float* __restrict__ c2bih, const float* __restrict__ c2bhh,
    const float* __restrict__ linW, const float* __restrict__ linb,
    char* ws, float* __restrict__ out) {
  extern __shared__ char dynlds[];
  unsigned short* As = (unsigned short*)(dynlds + A_OFF);
  float (*red)[2][4][64] = reinterpret_cast<float(*)[2][4][64]>(dynlds + RED_OFF);

  GBar* bar = (GBar*)(ws + OFF_BAR);
  float* h1f0 = (float*)(ws + OFF_H1F);
  float* h1f1 = h1f0 + (size_t)B_ * H_;
  float* h2f0 = (float*)(ws + OFF_H2F);
  float* h2f1 = h2f0 + (size_t)B_ * H_;
  float* c1f = (float*)(ws + OFF_C1);
  float* c2f = (float*)(ws + OFF_C2);
  float* x1f = (float*)(ws + OFF_X1F);
  float* x2f = (float*)(ws + OFF_X2F);
  unsigned short* h1s0 = (unsigned short*)(ws + OFF_H1S);
  unsigned short* h1s1 = h1s0 + (size_t)B_ * H_;
  unsigned short* h2s0 = (unsigned short*)(ws + OFF_H2S);
  unsigned short* h2s1 = h2s0 + (size_t)B_ * H_;
  unsigned short* x1s = (unsigned short*)(ws + OFF_X1S);
  unsigned short* x2s = (unsigned short*)(ws + OFF_X2S);
  float* bs1 = (float*)(ws + OFF_BS1);
  float* bs2 = (float*)(ws + OFF_BS2);
  unsigned short* wq1 = (unsigned short*)(ws + OFF_WQ1);
  unsigned short* wr1 = (unsigned short*)(ws + OFF_WR1);
  unsigned short* wih1 = (unsigned short*)(ws + OFF_WIH1);
  unsigned short* whh1 = (unsigned short*)(ws + OFF_WHH1);
  unsigned short* wq2 = (unsigned short*)(ws + OFF_WQ2);
  unsigned short* wr2 = (unsigned short*)(ws + OFF_WR2);
  unsigned short* wih2 = (unsigned short*)(ws + OFF_WIH2);
  unsigned short* whh2 = (unsigned short*)(ws + OFF_WHH2);

  const int wg = blockIdx.x;

  // ---- init: fp32 -> bf16 weight conversion (plain stores) + bias sums
  {
    size_t gt = (size_t)wg * WGS + threadIdx.x;
    const size_t gs = (size_t)NWG * WGS;
    const float* srcs[8] = {c1Q, c1R, c1Wih, c1Whh, c2Q, c2R, c2Wih, c2Whh};
    unsigned short* dsts[8] = {wq1, wr1, wih1, whh1, wq2, wr2, wih2, whh2};
    const size_t cnts[8] = {3ull * I_ * H_, 2ull * H_ * I_, (size_t)G_ * I_,
                            (size_t)G_ * H_, 3ull * H_ * H_, 2ull * H_ * H_,
                            (size_t)G_ * H_, (size_t)G_ * H_};
    for (int a = 0; a < 8; a++)
      for (size_t i = gt; i < cnts[a]; i += gs) dsts[a][i] = f2bf(srcs[a][i]);
    for (size_t i = gt; i < (size_t)G_; i += gs) bs1[i] = c1bih[i] + c1bhh[i];
    for (size_t i = gt; i < (size_t)G_; i += gs) bs2[i] = c2bih[i] + c2bhh[i];
  }
  gbar_init(bar);  // full fences ONCE: publish plain-stored weights

  // phase p: layer-1 step p and layer-2 step p-1 concurrently; 6 phases/step.
  // WG roles (nb = low bits -> XCD-stable W slices, L2-resident):
  //   mog2  (s<5, doL2): WGs 0..63    (mt=wg>>3, ntBase=(wg&7)*8)
  //   mog1Q (s even, doL1): WGs 64..71 (mt=wg-64, ntBase=0, N=128)
  //   mog1R (s odd, doL1): WGs 128..191 (mt=(wg-128)>>3, ntBase=((wg-128)&7)*8)
  //   cell1 (s==5, doL1): WGs 0..127  (mt=wg>>4, nb=wg&15)
  //   cell2 (s==5, doL2): WGs 128..255 (mt=(wg-128)>>4, nb=(wg-128)&15)
  for (int p = 0; p <= T_; ++p) {
    const int q = p & 1;
    const int q2 = 1 - q;
    const bool doL1 = (p < T_);
    const bool doL2 = (p > 0);
    float* h1q = q ? h1f1 : h1f0;
    float* h1o = q ? h1f0 : h1f1;
    unsigned short* h1sq = q ? h1s1 : h1s0;
    unsigned short* h1so = q ? h1s0 : h1s1;
    float* h2q2 = q2 ? h2f1 : h2f0;
    float* h2o = q ? h2f1 : h2f0;
    unsigned short* h2sq2 = q2 ? h2s1 : h2s0;
    unsigned short* h2so = q ? h2s1 : h2s0;

    for (int s = 0; s < 6; ++s) {
      if (s < 5) {
        const int r = s >> 1;
        if (s & 1) {  // R rounds
          if (doL2 && wg < 64)
            mog_wl<1024>(x2s, wr2 + (size_t)r * H_ * H_, c2Rb + r * H_,
                         h2q2, H_, h2q2, h2sq2, H_, wg >> 3, (wg & 7) * 8, As);
          if (doL1 && wg >= 128 && wg < 192)
            mog_wl<128>(x1s, wr1 + (size_t)r * H_ * I_, c1Rb + r * H_,
                        h1q, H_, h1q, h1sq, H_, (wg - 128) >> 3, ((wg - 128) & 7) * 8, As);
        } else {      // Q rounds
          if (doL2 && wg < 64)
            mog_wl<1024>(h2sq2, wq2 + (size_t)r * H_ * H_, c2Qb + r * H_,
                         (r == 0) ? h1q : x2f, H_, x2f, x2s, H_, wg >> 3, (wg & 7) * 8, As);
          if (doL1 && wg >= 64 && wg < 72)
            mog_wl<1024>(h1sq, wq1 + (size_t)r * I_ * H_, c1Qb + r * I_,
                         (r == 0) ? (in_seq + (size_t)p * I_) : x1f,
                         (r == 0) ? T_ * I_ : I_, x1f, x1s, I_, wg - 64, 0, As);
        }
      } else {  // s == 5: both cells concurrently on disjoint WG halves
        if (doL1 && wg < 128)
          cell_wl<1>(x1s, h1sq, wih1, whh1, bs1, c1f, h1o, h1so,
                     wg >> 4, wg & 15, As, red);
        if (doL2 && wg >= 128)
          cell_wl<2>(x2s, h2sq2, wih2, whh2, bs2, c2f, h2o, h2so,
                     (wg - 128) >> 4, (wg - 128) & 15, As, red);
      }
      gbar_fast(bar);
    }
  }

  // ---- final linear: out[b] = dot(h2_final[b,:], linW) + linb (parity 0)
  if (wg == 0) {
    float* rf = (float*)dynlds;
    const int tid = threadIdx.x;
    const int b = tid >> 2, qq = tid & 3;
    const float* row = h2f0 + (size_t)b * H_ + qq * 256;
    const float* w = linW + qq * 256;
    float s = 0.f;
    for (int k = 0; k < 256; k++) s += cloadf(&row[k]) * w[k];
    rf[tid] = s;
    __syncthreads();
    if (tid < B_)
      out[tid] = rf[tid * 4] + rf[tid * 4 + 1] + rf[tid * 4 + 2] + rf[tid * 4 + 3] + linb[0];
  }
}

extern "C" void kernel_launch(void* const* d_in, const int* in_sizes, int n_in,
                              void* d_out, int out_size, void* d_ws, size_t ws_size,
                              hipStream_t stream) {
  const float* in_seq = (const float*)d_in[0];
  const float* c1Q = (const float*)d_in[1];
  const float* c1Qb = (const float*)d_in[2];
  const float* c1R = (const float*)d_in[3];
  const float* c1Rb = (const float*)d_in[4];
  const float* c1Wih = (const float*)d_in[5];
  const float* c1Whh = (const float*)d_in[6];
  const float* c1bih = (const float*)d_in[7];
  const float* c1bhh = (const float*)d_in[8];
  const float* c2Q = (const float*)d_in[9];
  const float* c2Qb = (const float*)d_in[10];
  const float* c2R = (const float*)d_in[11];
  const float* c2Rb = (const float*)d_in[12];
  const float* c2Wih = (const float*)d_in[13];
  const float* c2Whh = (const float*)d_in[14];
  const float* c2bih = (const float*)d_in[15];
  const float* c2bhh = (const float*)d_in[16];
  const float* linW = (const float*)d_in[17];
  const float* linb = (const float*)d_in[18];

  static_assert(DYN_LDS == 82176, "lds layout");
  hipFuncSetAttribute((const void*)moglstm_kernel,
                      hipFuncAttributeMaxDynamicSharedMemorySize, (int)DYN_LDS);
  hipMemsetAsync(d_ws, 0, ZERO_BYTES, stream);
  moglstm_kernel<<<dim3(NWG), dim3(WGS), DYN_LDS, stream>>>(
      in_seq, c1Q, c1Qb, c1R, c1Rb, c1Wih, c1Whh, c1bih, c1bhh,
      c2Q, c2Qb, c2R, c2Rb, c2Wih, c2Whh, c2bih, c2bhh,
      linW, linb, (char*)d_ws, (float*)d_out);
}